// Round 3
// baseline (232.271 us; speedup 1.0000x reference)
//
#include <hip/hip_runtime.h>
#include <cmath>

#define C_CLASSES 21
#define EPS 1e-12f
#define IGNORE_INDEX (-1)
#define THREADS 256
#define EPT 16   // elements per thread

// d_ws layout: [0 .. nblocks) float2 {partial_sum, partial_count}.
// Every block writes its own slot -> no zero-init dispatch, no atomics.
// count fits exactly in f32: <= EPT*THREADS = 4096 per block.

__global__ __launch_bounds__(THREADS) void pcl_reduce_kernel(
    const float* __restrict__ input,     // [N, 21] — only column 0, only for t==0 rows
    const float* __restrict__ weight,    // [N]
    const float* __restrict__ pc_input,  // [4096] — cache-resident
    const int*   __restrict__ target,    // [N]
    const int*   __restrict__ cluster,   // [N]
    float2* __restrict__ part,           // [gridDim.x]
    int n)
{
    const int tid  = blockIdx.x * THREADS + threadIdx.x;
    const int base = tid * EPT;

    float lsum = 0.0f;
    int   lcnt = 0;

    if (base + EPT - 1 < n) {
        int   ts[EPT];
        int   cs[EPT];
        float wv[EPT];
        // coalesced 16B vector loads; issue all loads first for max ILP
#pragma unroll
        for (int q = 0; q < EPT / 4; ++q) {
            const int4   t4 = *reinterpret_cast<const int4*>(target + base + 4 * q);
            const int4   c4 = *reinterpret_cast<const int4*>(cluster + base + 4 * q);
            const float4 w4 = *reinterpret_cast<const float4*>(weight + base + 4 * q);
            ts[4*q+0]=t4.x; ts[4*q+1]=t4.y; ts[4*q+2]=t4.z; ts[4*q+3]=t4.w;
            cs[4*q+0]=c4.x; cs[4*q+1]=c4.y; cs[4*q+2]=c4.z; cs[4*q+3]=c4.w;
            wv[4*q+0]=w4.x; wv[4*q+1]=w4.y; wv[4*q+2]=w4.z; wv[4*q+3]=w4.w;
        }

#pragma unroll
        for (int j = 0; j < EPT; ++j) {
            const int t = ts[j];
            if (t == IGNORE_INDEX) continue;
            ++lcnt;
            float p;
            if (t == 0) {
                // background: scattered predicated load, ~1/21 of lanes
                p = input[(size_t)(base + j) * C_CLASSES];
            } else {
                // foreground: 16KB table gather, cache-resident
                p = pc_input[cs[j]];
            }
            lsum -= wv[j] * logf(fmaxf(p, EPS));
        }
    } else if (base < n) {
        for (int j = 0; j < EPT && base + j < n; ++j) {
            const int i = base + j;
            const int t = target[i];
            if (t == IGNORE_INDEX) continue;
            ++lcnt;
            float p = (t == 0) ? input[(size_t)i * C_CLASSES]
                               : pc_input[cluster[i]];
            lsum -= weight[i] * logf(fmaxf(p, EPS));
        }
    }

    // wave64 shuffle reduction
    float fcnt = (float)lcnt;
#pragma unroll
    for (int off = 32; off > 0; off >>= 1) {
        lsum += __shfl_down(lsum, off, 64);
        fcnt += __shfl_down(fcnt, off, 64);
    }

    __shared__ float2 sred[THREADS / 64];
    const int wave = threadIdx.x >> 6;
    const int lane = threadIdx.x & 63;
    if (lane == 0) sred[wave] = make_float2(lsum, fcnt);
    __syncthreads();

    if (threadIdx.x == 0) {
        float bs = 0.0f, bc = 0.0f;
#pragma unroll
        for (int w = 0; w < THREADS / 64; ++w) { bs += sred[w].x; bc += sred[w].y; }
        part[blockIdx.x] = make_float2(bs, bc);
    }
}

__global__ __launch_bounds__(THREADS) void pcl_finalize_kernel(
    const float2* __restrict__ part,
    float* __restrict__ out,
    int nblocks)
{
    double lsum = 0.0, lcnt = 0.0;
    for (int i = threadIdx.x; i < nblocks; i += THREADS) {
        const float2 p = part[i];
        lsum += (double)p.x;
        lcnt += (double)p.y;
    }
#pragma unroll
    for (int off = 32; off > 0; off >>= 1) {
        lsum += __shfl_down(lsum, off, 64);
        lcnt += __shfl_down(lcnt, off, 64);
    }
    __shared__ double ssum[THREADS / 64];
    __shared__ double scnt[THREADS / 64];
    const int wave = threadIdx.x >> 6;
    const int lane = threadIdx.x & 63;
    if (lane == 0) { ssum[wave] = lsum; scnt[wave] = lcnt; }
    __syncthreads();
    if (threadIdx.x == 0) {
        double s = 0.0, c = 0.0;
#pragma unroll
        for (int w = 0; w < THREADS / 64; ++w) { s += ssum[w]; c += scnt[w]; }
        if (c < 1.0) c = 1.0;
        out[0] = (float)(s / c);
    }
}

extern "C" void kernel_launch(void* const* d_in, const int* in_sizes, int n_in,
                              void* d_out, int out_size, void* d_ws, size_t ws_size,
                              hipStream_t stream) {
    const float* input    = (const float*)d_in[0];
    const float* weight   = (const float*)d_in[1];
    const float* pc_input = (const float*)d_in[2];
    const int*   target   = (const int*)d_in[3];
    const int*   cluster  = (const int*)d_in[4];
    float* out = (float*)d_out;

    const int n = in_sizes[1];  // weight has N elements

    const int groups = (n + EPT - 1) / EPT;
    const int blocks = (groups + THREADS - 1) / THREADS;  // 512 for N=2^21

    float2* part = (float2*)d_ws;

    pcl_reduce_kernel<<<blocks, THREADS, 0, stream>>>(
        input, weight, pc_input, target, cluster, part, n);

    pcl_finalize_kernel<<<1, THREADS, 0, stream>>>(part, out, blocks);
}